// Round 5
// baseline (283.689 us; speedup 1.0000x reference)
//
#include <hip/hip_runtime.h>
#include <math.h>

// Problem constants
#define T_NODES 2048
#define M_WORDS 32
#define D 768
#define DTRAJ 256
#define NCHUNK 128

typedef __attribute__((ext_vector_type(8))) short bhalf8;
typedef __attribute__((ext_vector_type(4))) float f32x4;

#define AS1 __attribute__((address_space(1)))
#define AS3 __attribute__((address_space(3)))

// ---------------- Workspace layout (byte offsets) ----------------
constexpr size_t OFF_A1HI = 0;                                        // 2048x256 bf16
constexpr size_t OFF_A1LO = OFF_A1HI + (size_t)T_NODES * DTRAJ * 2;
constexpr size_t OFF_AHI  = OFF_A1LO + (size_t)T_NODES * DTRAJ * 2;   // 2048x768 bf16
constexpr size_t OFF_ALO  = OFF_AHI + (size_t)T_NODES * D * 2;
constexpr size_t OFF_WT1H = OFF_ALO + (size_t)T_NODES * D * 2;        // 768x256 bf16
constexpr size_t OFF_WT1L = OFF_WT1H + (size_t)D * DTRAJ * 2;
constexpr size_t OFF_WT2H = OFF_WT1L + (size_t)D * DTRAJ * 2;         // 768x768 x6
constexpr size_t OFF_WT2L = OFF_WT2H + (size_t)D * D * 2;
constexpr size_t OFF_WG0H = OFF_WT2L + (size_t)D * D * 2;
constexpr size_t OFF_WG0L = OFF_WG0H + (size_t)D * D * 2;
constexpr size_t OFF_WG1H = OFF_WG0L + (size_t)D * D * 2;
constexpr size_t OFF_WG1L = OFF_WG1H + (size_t)D * D * 2;
constexpr size_t OFF_BUFB = OFF_WG1L + (size_t)D * D * 2;             // 2048x768 f32
constexpr size_t OFF_ALPH = OFF_BUFB + (size_t)T_NODES * D * 4;       // 2048x32 f32
constexpr size_t OFF_WPRT = OFF_ALPH + (size_t)T_NODES * M_WORDS * 4; // 128x32x768 f32
constexpr size_t OFF_BPRT = OFF_WPRT + (size_t)NCHUNK * M_WORDS * D * 4;
constexpr size_t OFF_INVW = OFF_BPRT + (size_t)NCHUNK * M_WORDS * 4;

__device__ __forceinline__ float gelu_exact(float x) {
    return 0.5f * x * (1.0f + erff(x * 0.70710678118654752f));
}
__device__ __forceinline__ unsigned short f2bf(float x) {  // RNE
    unsigned int u = __float_as_uint(x);
    return (unsigned short)((u + 0x7fffu + ((u >> 16) & 1u)) >> 16);
}
__device__ __forceinline__ float bf2f(unsigned short b) {
    return __uint_as_float(((unsigned int)b) << 16);
}
__device__ __forceinline__ void stage16(const unsigned short* g, short* l) {
    // async global->LDS, 16B/lane; LDS dest = wave-uniform base + lane*16
    __builtin_amdgcn_global_load_lds((const AS1 void*)g, (AS3 void*)l, 16, 0, 0);
}

__device__ __forceinline__ float wave_reduce_sum(float v) {
#pragma unroll
    for (int off = 32; off > 0; off >>= 1) v += __shfl_down(v, off);
    return v;  // lane 0
}
__device__ __forceinline__ float block_reduce_sum256(float v, float* sbuf) {
    v = wave_reduce_sum(v);
    const int lane = threadIdx.x & 63, wid = threadIdx.x >> 6;
    if (lane == 0) sbuf[wid] = v;
    __syncthreads();
    float r = sbuf[0] + sbuf[1] + sbuf[2] + sbuf[3];
    __syncthreads();
    return r;
}

// LayerNorm of one 768 row, 256 threads (3 elems/thread)
__device__ __forceinline__ void ln_row(const float* __restrict__ x,
                                       const float* __restrict__ g,
                                       const float* __restrict__ b, float* sbuf,
                                       float& y0, float& y1, float& y2) {
    const int tid = threadIdx.x;
    const float x0 = x[tid], x1 = x[tid + 256], x2 = x[tid + 512];
    const float s = block_reduce_sum256(x0 + x1 + x2, sbuf);
    const float mu = s * (1.0f / 768.0f);
    const float d0 = x0 - mu, d1 = x1 - mu, d2 = x2 - mu;
    const float v = block_reduce_sum256(d0 * d0 + d1 * d1 + d2 * d2, sbuf);
    const float rs = rsqrtf(v * (1.0f / 768.0f) + 1e-5f);
    y0 = d0 * rs * g[tid] + b[tid];
    y1 = d1 * rs * g[tid + 256] + b[tid + 256];
    y2 = d2 * rs * g[tid + 512] + b[tid + 512];
}

// ---------------- prep: all input conversions + word norms (one launch) ----
// blocks [0,512): traj fp32 -> hi/lo split (flat)
// blocks [512,704): W1 (256x768) -> Wt1 (768x256) hi/lo
// blocks [704,2432): W2,g0_W,g1_W (768x768) -> transposed hi/lo
// blocks [2432,2464): word row inv-norms
__device__ __forceinline__ void tr_split_tile2(const float* __restrict__ W,
                                               unsigned short* __restrict__ hi,
                                               unsigned short* __restrict__ lo, int K,
                                               int N, int n0, int k0, float* tile) {
    const int tx = threadIdx.x & 31, ty = threadIdx.x >> 5;  // ty 0..7
#pragma unroll
    for (int i = 0; i < 32; i += 8)
        tile[(ty + i) * 33 + tx] = W[(size_t)(k0 + ty + i) * N + n0 + tx];
    __syncthreads();
#pragma unroll
    for (int i = 0; i < 32; i += 8) {
        const float v = tile[tx * 33 + ty + i];
        const unsigned short h = f2bf(v);
        const size_t o = (size_t)(n0 + ty + i) * K + k0 + tx;
        hi[o] = h;
        lo[o] = f2bf(v - bf2f(h));
    }
}

__global__ __launch_bounds__(256) void prep_kernel(
    const float* __restrict__ traj, const float* __restrict__ W1,
    const float* __restrict__ W2, const float* __restrict__ Wg0,
    const float* __restrict__ Wg1, const float* __restrict__ words,
    unsigned short* __restrict__ A1hi, unsigned short* __restrict__ A1lo,
    unsigned short* __restrict__ WT1h, unsigned short* __restrict__ WT1l,
    unsigned short* __restrict__ WT2h, unsigned short* __restrict__ WT2l,
    unsigned short* __restrict__ WG0h, unsigned short* __restrict__ WG0l,
    unsigned short* __restrict__ WG1h, unsigned short* __restrict__ WG1l,
    float* __restrict__ invw) {
    __shared__ float tile[32 * 33];
    __shared__ float sbuf[4];
    const int blk = blockIdx.x;
    if (blk < 512) {
        const int i = (blk * 256 + threadIdx.x) * 4;
        const float4 v = *(const float4*)(traj + i);
        ushort4 h, l;
        h.x = f2bf(v.x); l.x = f2bf(v.x - bf2f(h.x));
        h.y = f2bf(v.y); l.y = f2bf(v.y - bf2f(h.y));
        h.z = f2bf(v.z); l.z = f2bf(v.z - bf2f(h.z));
        h.w = f2bf(v.w); l.w = f2bf(v.w - bf2f(h.w));
        *(ushort4*)(A1hi + i) = h;
        *(ushort4*)(A1lo + i) = l;
    } else if (blk < 704) {
        const int idx = blk - 512;
        tr_split_tile2(W1, WT1h, WT1l, DTRAJ, D, (idx % 24) * 32, (idx / 24) * 32, tile);
    } else if (blk < 2432) {
        const int idx = blk - 704;
        const int wsel = idx / 576, rem = idx % 576;
        const float* W = (wsel == 0) ? W2 : (wsel == 1) ? Wg0 : Wg1;
        unsigned short* hi = (wsel == 0) ? WT2h : (wsel == 1) ? WG0h : WG1h;
        unsigned short* lo = (wsel == 0) ? WT2l : (wsel == 1) ? WG0l : WG1l;
        tr_split_tile2(W, hi, lo, D, D, (rem % 24) * 32, (rem / 24) * 32, tile);
    } else {
        const int w = blk - 2432;
        const size_t src = (size_t)w * D + threadIdx.x;
        const float x0 = words[src], x1 = words[src + 256], x2 = words[src + 512];
        const float ss = block_reduce_sum256(x0 * x0 + x1 * x1 + x2 * x2, sbuf);
        if (threadIdx.x == 0) invw[w] = 1.0f / fmaxf(sqrtf(ss), 1e-12f);
    }
}

// ---------------- MFMA split-bf16 GEMM (v3) ----------------
// C[2048 x 768] = act(A @ B + bias). A hi/lo row-major (lda=K_); B TRANSPOSED
// hi/lo (768 x K_). Tile 64(M)x96(N), grid (32,8) = 256 blocks (1/CU).
// 128 thr = 2 waves, each 64x48 out (4x3 frags of 16x16x32). BK=32,
// double-buffered, staged via global_load_lds (16B/lane).
// LDS k-chunk XOR swizzle (T2, both-sides): storage slot q of row holds
// global chunk q ^ s(row), s(row)=((row&15)>>1)&3, applied on the per-lane
// global SOURCE address; reads XOR the same way -> (lane,j)->k map stays the
// standard one for A and B, and ds_read_b128 is bank-conflict-free.
#define MFMA_BF16(a, b, c) __builtin_amdgcn_mfma_f32_16x16x32_bf16(a, b, c, 0, 0, 0)

template <int EPI, bool TRIM>
__global__ __launch_bounds__(128) void mfma_gemm(
    const unsigned short* __restrict__ Ahi, const unsigned short* __restrict__ Alo,
    const unsigned short* __restrict__ Bthi, const unsigned short* __restrict__ Btlo,
    const float* __restrict__ bias, float* __restrict__ C,
    unsigned short* __restrict__ Ohi, unsigned short* __restrict__ Olo, int K_,
    const int* __restrict__ vlp) {
    const int bm = blockIdx.x * 64;
    if (TRIM && bm >= *vlp) return;  // rows >= valid_len never consumed
    __shared__ short sA[2][2][64 * 32];  // [buf][hi/lo][row*32+k]
    __shared__ short sB[2][2][96 * 32];
    const int bn = blockIdx.y * 96;
    const int tid = threadIdx.x;
    const int wv = tid >> 6, lane = tid & 63;
    const int lrow = lane >> 2;
    const int lchunk = (((lane & 3) ^ ((lrow >> 1) & 3)) << 3);  // src k-offset
    const int g = lane >> 4, r = lane & 15;
    const int aoff = ((g ^ ((r >> 1) & 3)) << 3);  // frag-read k-offset
    const int wn = wv * 48;

    f32x4 acc[4][3];
#pragma unroll
    for (int i = 0; i < 4; ++i)
#pragma unroll
        for (int j = 0; j < 3; ++j) acc[i][j] = (f32x4){0.f, 0.f, 0.f, 0.f};

#define STAGE(buf, k0)                                                                     \
    if (wv == 0) {                                                                         \
        _Pragma("unroll") for (int i = 0; i < 4; ++i)                                      \
            stage16(Ahi + (size_t)(bm + i * 16 + lrow) * K_ + (k0) + lchunk,               \
                    &sA[buf][0][i * 512]);                                                 \
        _Pragma("unroll") for (int i = 0; i < 4; ++i)                                      \
            stage16(Alo + (size_t)(bm + i * 16 + lrow) * K_ + (k0) + lchunk,               \
                    &sA[buf][1][i * 512]);                                                 \
        _Pragma("unroll") for (int i = 0; i < 2; ++i)                                      \
            stage16(Bthi + (size_t)(bn + i * 16 + lrow) * K_ + (k0) + lchunk,              \
                    &sB[buf][0][i * 512]);                                                 \
    } else {                                                                               \
        _Pragma("unroll") for (int i = 2; i < 6; ++i)                                      \
            stage16(Bthi + (size_t)(bn + i * 16 + lrow) * K_ + (k0) + lchunk,              \
                    &sB[buf][0][i * 512]);                                                 \
        _Pragma("unroll") for (int i = 0; i < 6; ++i)                                      \
            stage16(Btlo + (size_t)(bn + i * 16 + lrow) * K_ + (k0) + lchunk,              \
                    &sB[buf][1][i * 512]);                                                 \
    }

    const int NT = K_ >> 5;
    STAGE(0, 0)
    __syncthreads();
    int cur = 0;
    for (int kt = 0; kt < NT; ++kt) {
        if (kt + 1 < NT) { STAGE(cur ^ 1, (kt + 1) << 5) }  // issue BEFORE compute
        bhalf8 af[4][2];
#pragma unroll
        for (int fm = 0; fm < 4; ++fm) {
            af[fm][0] = *(const bhalf8*)(void*)&sA[cur][0][(fm * 16 + r) * 32 + aoff];
            af[fm][1] = *(const bhalf8*)(void*)&sA[cur][1][(fm * 16 + r) * 32 + aoff];
        }
#pragma unroll
        for (int fn = 0; fn < 3; ++fn) {
            const bhalf8 bh = *(const bhalf8*)(void*)&sB[cur][0][(wn + fn * 16 + r) * 32 + aoff];
            const bhalf8 bl = *(const bhalf8*)(void*)&sB[cur][1][(wn + fn * 16 + r) * 32 + aoff];
#pragma unroll
            for (int fm = 0; fm < 4; ++fm) {
                acc[fm][fn] = MFMA_BF16(af[fm][0], bh, acc[fm][fn]);
                acc[fm][fn] = MFMA_BF16(af[fm][0], bl, acc[fm][fn]);
                acc[fm][fn] = MFMA_BF16(af[fm][1], bh, acc[fm][fn]);
            }
        }
        __syncthreads();  // vmcnt(0)+lgkmcnt(0)+barrier: next tile landed, reads done
        cur ^= 1;
    }
#undef STAGE

    // C/D layout (HW-verified m89/m91): col = lane&15, row = 4*(lane>>4)+reg
#pragma unroll
    for (int fm = 0; fm < 4; ++fm)
#pragma unroll
        for (int fn = 0; fn < 3; ++fn) {
            const int col = bn + wn + fn * 16 + r;
            const float bv = bias[col];
#pragma unroll
            for (int j = 0; j < 4; ++j) {
                const int row = bm + fm * 16 + g * 4 + j;
                float v = acc[fm][fn][j] + bv;
                if (EPI == 0) {
                    C[(size_t)row * D + col] = v;
                } else {
                    v = gelu_exact(v);
                    const unsigned short h = f2bf(v);
                    Ohi[(size_t)row * D + col] = h;
                    Olo[(size_t)row * D + col] = f2bf(v - bf2f(h));
                }
            }
        }
}

// ---------------- fused init (LN*scale -> h) + row softmax -> alpha -----------
__global__ __launch_bounds__(256) void init_softmax(
    const float* __restrict__ z, const float* __restrict__ g,
    const float* __restrict__ b, const float* __restrict__ tsp,
    const float* __restrict__ words, const float* __restrict__ invw,
    const int* __restrict__ vlp, float* __restrict__ h, float* __restrict__ alpha) {
    __shared__ float sbuf[4];
    __shared__ float row[D];
    __shared__ float logits[M_WORDS];
    const int blk = blockIdx.x, tid = threadIdx.x;
    if (blk >= T_NODES) {  // word rows: copy into h
        const int w = blk - T_NODES;
        const size_t src = (size_t)w * D + tid;
        const size_t dst = (size_t)(T_NODES + w) * D + tid;
        h[dst] = words[src];
        h[dst + 256] = words[src + 256];
        h[dst + 512] = words[src + 512];
        return;
    }
    float y0, y1, y2;
    ln_row(z + (size_t)blk * D, g, b, sbuf, y0, y1, y2);
    const float sc = fminf(fmaxf(tsp[0], 0.05f), 2.0f);
    y0 *= sc; y1 *= sc; y2 *= sc;
    const size_t o = (size_t)blk * D + tid;
    h[o] = y0; h[o + 256] = y1; h[o + 512] = y2;
    const float ss = block_reduce_sum256(y0 * y0 + y1 * y1 + y2 * y2, sbuf);
    const float iz = 1.0f / fmaxf(sqrtf(ss), 1e-12f);
    if (blk >= *vlp) return;  // alpha rows >= VL never read
    row[tid] = y0; row[tid + 256] = y1; row[tid + 512] = y2;
    __syncthreads();
    const int wid = tid >> 6, lane = tid & 63;
#pragma unroll
    for (int i = 0; i < 8; ++i) {
        const int w = wid * 8 + i;
        const float* wr = words + (size_t)w * D;
        float dot = 0.0f;
        for (int e = lane; e < D; e += 64) dot = fmaf(row[e], wr[e], dot);
        dot = wave_reduce_sum(dot);
        if (lane == 0) logits[w] = dot * iz * invw[w];  // TAU = 1
    }
    __syncthreads();
    if (tid < 64) {
        const float val = (tid < 32) ? logits[tid] : -INFINITY;
        float mx = val;
#pragma unroll
        for (int off = 32; off > 0; off >>= 1) mx = fmaxf(mx, __shfl_xor(mx, off));
        const float e = (tid < 32) ? expf(val - mx) : 0.0f;
        float sum = e;
#pragma unroll
        for (int off = 32; off > 0; off >>= 1) sum += __shfl_xor(sum, off);
        if (tid < 32) alpha[(size_t)blk * M_WORDS + tid] = e / sum;
    }
}

// -------- LN(h)->split bf16 (traj rows); FIN: word rows apply prev-layer fin --
template <int FIN>
__global__ __launch_bounds__(256) void ln_split_fin(
    const float* __restrict__ x, const float* __restrict__ g,
    const float* __restrict__ b, unsigned short* __restrict__ hi,
    unsigned short* __restrict__ lo, const float* __restrict__ wpart,
    const float* __restrict__ bpart, float* __restrict__ h) {
    __shared__ float sbuf[4];
    const int blk = blockIdx.x, tid = threadIdx.x;
    if (blk < T_NODES) {
        float y0, y1, y2;
        ln_row(x + (size_t)blk * D, g, b, sbuf, y0, y1, y2);
        const size_t o = (size_t)blk * D + tid;
        unsigned short hh;
        hh = f2bf(y0); hi[o] = hh;       lo[o] = f2bf(y0 - bf2f(hh));
        hh = f2bf(y1); hi[o + 256] = hh; lo[o + 256] = f2bf(y1 - bf2f(hh));
        hh = f2bf(y2); hi[o + 512] = hh; lo[o + 512] = f2bf(y2 - bf2f(hh));
    } else if (FIN) {
        const int w = blk - T_NODES;
        float bsum = (tid < NCHUNK) ? bpart[tid * M_WORDS + w] : 0.0f;
        const float beta = block_reduce_sum256(bsum, sbuf);
        const float ib = fminf(fmaxf(1.0f / (beta + 1e-6f), 0.2f), 5.0f);
        const float scl = ib / fmaxf(beta, 1.0f);
#pragma unroll
        for (int i = 0; i < 3; ++i) {
            const int c = tid + i * 256;
            float acc = 0.0f;
#pragma unroll 8
            for (int q = 0; q < NCHUNK; ++q)
                acc += wpart[((size_t)q * M_WORDS + w) * D + c];
            h[(size_t)(T_NODES + w) * D + c] += gelu_exact(acc * scl);
        }
    }
}

// -------- per-layer aggregation: temporal update + semantic partials ---------
__global__ __launch_bounds__(256) void gcn_agg_kernel(const float* __restrict__ m,
                                                      const float* __restrict__ alpha,
                                                      const int* __restrict__ vlp,
                                                      float* __restrict__ h,
                                                      float* __restrict__ wpart,
                                                      float* __restrict__ bpart) {
    const int VL = *vlp;
    const int chunk = blockIdx.x, cb = blockIdx.y;
    const int c = cb * 256 + threadIdx.x;
    const int tpc = (VL + NCHUNK - 1) / NCHUNK;
    const int t0 = chunk * tpc;
    const int t1 = min(t0 + tpc, VL);
    float acc[M_WORDS] = {};
    for (int t = t0; t < t1; ++t) {
        const float mv = m[(size_t)t * D + c];
        if (t + 1 < VL) h[(size_t)(t + 1) * D + c] += gelu_exact(mv);
        const float4* a4 = (const float4*)(alpha + (size_t)t * M_WORDS);
#pragma unroll
        for (int q = 0; q < 8; ++q) {
            const float4 a = a4[q];
            acc[q * 4 + 0] = fmaf(a.x, mv, acc[q * 4 + 0]);
            acc[q * 4 + 1] = fmaf(a.y, mv, acc[q * 4 + 1]);
            acc[q * 4 + 2] = fmaf(a.z, mv, acc[q * 4 + 2]);
            acc[q * 4 + 3] = fmaf(a.w, mv, acc[q * 4 + 3]);
        }
    }
#pragma unroll
    for (int w = 0; w < M_WORDS; ++w)
        wpart[((size_t)chunk * M_WORDS + w) * D + c] = acc[w];
    if (cb == 0 && threadIdx.x < M_WORDS) {
        float bs = 0.0f;
        for (int t = t0; t < t1; ++t) bs += alpha[(size_t)t * M_WORDS + threadIdx.x];
        bpart[chunk * M_WORDS + threadIdx.x] = bs;
    }
}

// final-layer word update (h output rows)
__global__ __launch_bounds__(256) void word_fin_kernel(const float* __restrict__ wpart,
                                                       const float* __restrict__ bpart,
                                                       float* __restrict__ h) {
    const int idx = blockIdx.x * 256 + threadIdx.x;
    const int w = idx / D, c = idx - w * D;
    float beta = 0.0f, acc = 0.0f;
#pragma unroll 8
    for (int q = 0; q < NCHUNK; ++q) {
        beta += bpart[q * M_WORDS + w];
        acc += wpart[((size_t)q * M_WORDS + w) * D + c];
    }
    const float ib = fminf(fmaxf(1.0f / (beta + 1e-6f), 0.2f), 5.0f);
    const float v = acc / fmaxf(beta, 1.0f) * ib;
    h[(size_t)(T_NODES + w) * D + c] += gelu_exact(v);
}

extern "C" void kernel_launch(void* const* d_in, const int* in_sizes, int n_in,
                              void* d_out, int out_size, void* d_ws, size_t ws_size,
                              hipStream_t stream) {
    const float* traj = (const float*)d_in[0];
    const float* words = (const float*)d_in[1];
    // d_in[2], d_in[3]: edge indices — deterministic structure, unused.
    const int* vlp = (const int*)d_in[4];
    const float* W1 = (const float*)d_in[5];
    const float* b1 = (const float*)d_in[6];
    const float* W2 = (const float*)d_in[7];
    const float* b2 = (const float*)d_in[8];
    const float* ln_g = (const float*)d_in[9];
    const float* ln_b = (const float*)d_in[10];
    const float* tsc = (const float*)d_in[11];
    const float* g_ln_g[2] = {(const float*)d_in[12], (const float*)d_in[16]};
    const float* g_ln_b[2] = {(const float*)d_in[13], (const float*)d_in[17]};
    const float* g_W[2] = {(const float*)d_in[14], (const float*)d_in[18]};
    const float* g_b[2] = {(const float*)d_in[15], (const float*)d_in[19]};

    char* wsb = (char*)d_ws;
    unsigned short* A1hi = (unsigned short*)(wsb + OFF_A1HI);
    unsigned short* A1lo = (unsigned short*)(wsb + OFF_A1LO);
    unsigned short* Ahi = (unsigned short*)(wsb + OFF_AHI);
    unsigned short* Alo = (unsigned short*)(wsb + OFF_ALO);
    unsigned short* WT1h = (unsigned short*)(wsb + OFF_WT1H);
    unsigned short* WT1l = (unsigned short*)(wsb + OFF_WT1L);
    unsigned short* WT2h = (unsigned short*)(wsb + OFF_WT2H);
    unsigned short* WT2l = (unsigned short*)(wsb + OFF_WT2L);
    unsigned short* WG0h = (unsigned short*)(wsb + OFF_WG0H);
    unsigned short* WG0l = (unsigned short*)(wsb + OFF_WG0L);
    unsigned short* WG1h = (unsigned short*)(wsb + OFF_WG1H);
    unsigned short* WG1l = (unsigned short*)(wsb + OFF_WG1L);
    float* bufB = (float*)(wsb + OFF_BUFB);
    float* alpha = (float*)(wsb + OFF_ALPH);
    float* wpart = (float*)(wsb + OFF_WPRT);
    float* bpart = (float*)(wsb + OFF_BPRT);
    float* invw = (float*)(wsb + OFF_INVW);
    float* h = (float*)d_out;

    const unsigned short* WGh[2] = {WG0h, WG1h};
    const unsigned short* WGl[2] = {WG0l, WG1l};

    const dim3 ggrid(T_NODES / 64, D / 96);  // (32, 8) = 256 blocks

    // 1. all conversions + word norms
    prep_kernel<<<2464, 256, 0, stream>>>(traj, W1, W2, g_W[0], g_W[1], words, A1hi, A1lo,
                                          WT1h, WT1l, WT2h, WT2l, WG0h, WG0l, WG1h, WG1l,
                                          invw);
    // 2-3. MLP
    mfma_gemm<1, false><<<ggrid, 128, 0, stream>>>(A1hi, A1lo, WT1h, WT1l, b1, nullptr,
                                                   Ahi, Alo, DTRAJ, vlp);
    mfma_gemm<0, false><<<ggrid, 128, 0, stream>>>(Ahi, Alo, WT2h, WT2l, b2, bufB,
                                                   nullptr, nullptr, D, vlp);
    // 4. h init + alpha
    init_softmax<<<T_NODES + M_WORDS, 256, 0, stream>>>(bufB, ln_g, ln_b, tsc, words,
                                                        invw, vlp, h, alpha);
    // 5-7. GCN layer 0
    ln_split_fin<0><<<T_NODES, 256, 0, stream>>>(h, g_ln_g[0], g_ln_b[0], Ahi, Alo,
                                                 nullptr, nullptr, h);
    mfma_gemm<0, true><<<ggrid, 128, 0, stream>>>(Ahi, Alo, WGh[0], WGl[0], g_b[0], bufB,
                                                  nullptr, nullptr, D, vlp);
    gcn_agg_kernel<<<dim3(NCHUNK, 3), 256, 0, stream>>>(bufB, alpha, vlp, h, wpart, bpart);
    // 8-10. GCN layer 1 (word-fin of layer 0 fused into ln_split)
    ln_split_fin<1><<<T_NODES + M_WORDS, 256, 0, stream>>>(h, g_ln_g[1], g_ln_b[1], Ahi,
                                                           Alo, wpart, bpart, h);
    mfma_gemm<0, true><<<ggrid, 128, 0, stream>>>(Ahi, Alo, WGh[1], WGl[1], g_b[1], bufB,
                                                  nullptr, nullptr, D, vlp);
    gcn_agg_kernel<<<dim3(NCHUNK, 3), 256, 0, stream>>>(bufB, alpha, vlp, h, wpart, bpart);
    // 11. final word rows
    word_fin_kernel<<<(M_WORDS * D) / 256, 256, 0, stream>>>(wpart, bpart, h);
}

// Round 6
// 249.445 us; speedup vs baseline: 1.1373x; 1.1373x over previous
//
#include <hip/hip_runtime.h>
#include <math.h>

// Problem constants
#define T_NODES 2048
#define M_WORDS 32
#define D 768
#define DTRAJ 256
#define NCHUNK 128

typedef __attribute__((ext_vector_type(8))) short bhalf8;
typedef __attribute__((ext_vector_type(4))) float f32x4;

#define AS1 __attribute__((address_space(1)))
#define AS3 __attribute__((address_space(3)))

// ---------------- Workspace layout (byte offsets) ----------------
constexpr size_t OFF_A1HI = 0;                                        // 2048x256 bf16
constexpr size_t OFF_A1LO = OFF_A1HI + (size_t)T_NODES * DTRAJ * 2;
constexpr size_t OFF_AHI  = OFF_A1LO + (size_t)T_NODES * DTRAJ * 2;   // 2048x768 bf16
constexpr size_t OFF_ALO  = OFF_AHI + (size_t)T_NODES * D * 2;
constexpr size_t OFF_WT1H = OFF_ALO + (size_t)T_NODES * D * 2;        // 768x256 bf16
constexpr size_t OFF_WT1L = OFF_WT1H + (size_t)D * DTRAJ * 2;
constexpr size_t OFF_WT2H = OFF_WT1L + (size_t)D * DTRAJ * 2;         // 768x768 x6
constexpr size_t OFF_WT2L = OFF_WT2H + (size_t)D * D * 2;
constexpr size_t OFF_WG0H = OFF_WT2L + (size_t)D * D * 2;
constexpr size_t OFF_WG0L = OFF_WG0H + (size_t)D * D * 2;
constexpr size_t OFF_WG1H = OFF_WG0L + (size_t)D * D * 2;
constexpr size_t OFF_WG1L = OFF_WG1H + (size_t)D * D * 2;
constexpr size_t OFF_BUFB = OFF_WG1L + (size_t)D * D * 2;             // 2048x768 f32
constexpr size_t OFF_ALPH = OFF_BUFB + (size_t)T_NODES * D * 4;       // 2048x32 f32
constexpr size_t OFF_WPRT = OFF_ALPH + (size_t)T_NODES * M_WORDS * 4; // 128x32x768 f32
constexpr size_t OFF_BPRT = OFF_WPRT + (size_t)NCHUNK * M_WORDS * D * 4;
constexpr size_t OFF_INVW = OFF_BPRT + (size_t)NCHUNK * M_WORDS * 4;

__device__ __forceinline__ float gelu_exact(float x) {
    return 0.5f * x * (1.0f + erff(x * 0.70710678118654752f));
}
__device__ __forceinline__ unsigned short f2bf(float x) {  // RNE
    unsigned int u = __float_as_uint(x);
    return (unsigned short)((u + 0x7fffu + ((u >> 16) & 1u)) >> 16);
}
__device__ __forceinline__ float bf2f(unsigned short b) {
    return __uint_as_float(((unsigned int)b) << 16);
}
__device__ __forceinline__ void stage16(const unsigned short* g, short* l) {
    // async global->LDS, 16B/lane; LDS dest = wave-uniform base + lane*16
    __builtin_amdgcn_global_load_lds((const AS1 void*)g, (AS3 void*)l, 16, 0, 0);
}

__device__ __forceinline__ float wave_reduce_sum(float v) {
#pragma unroll
    for (int off = 32; off > 0; off >>= 1) v += __shfl_down(v, off);
    return v;  // lane 0
}
__device__ __forceinline__ float block_reduce_sum256(float v, float* sbuf) {
    v = wave_reduce_sum(v);
    const int lane = threadIdx.x & 63, wid = threadIdx.x >> 6;
    if (lane == 0) sbuf[wid] = v;
    __syncthreads();
    float r = sbuf[0] + sbuf[1] + sbuf[2] + sbuf[3];
    __syncthreads();
    return r;
}

// LayerNorm of one 768 row, 256 threads (3 elems/thread)
__device__ __forceinline__ void ln_row(const float* __restrict__ x,
                                       const float* __restrict__ g,
                                       const float* __restrict__ b, float* sbuf,
                                       float& y0, float& y1, float& y2) {
    const int tid = threadIdx.x;
    const float x0 = x[tid], x1 = x[tid + 256], x2 = x[tid + 512];
    const float s = block_reduce_sum256(x0 + x1 + x2, sbuf);
    const float mu = s * (1.0f / 768.0f);
    const float d0 = x0 - mu, d1 = x1 - mu, d2 = x2 - mu;
    const float v = block_reduce_sum256(d0 * d0 + d1 * d1 + d2 * d2, sbuf);
    const float rs = rsqrtf(v * (1.0f / 768.0f) + 1e-5f);
    y0 = d0 * rs * g[tid] + b[tid];
    y1 = d1 * rs * g[tid + 256] + b[tid + 256];
    y2 = d2 * rs * g[tid + 512] + b[tid + 512];
}

// ---------------- prep: all input conversions + word norms (one launch) ----
__device__ __forceinline__ void tr_split_tile2(const float* __restrict__ W,
                                               unsigned short* __restrict__ hi,
                                               unsigned short* __restrict__ lo, int K,
                                               int N, int n0, int k0, float* tile) {
    const int tx = threadIdx.x & 31, ty = threadIdx.x >> 5;  // ty 0..7
#pragma unroll
    for (int i = 0; i < 32; i += 8)
        tile[(ty + i) * 33 + tx] = W[(size_t)(k0 + ty + i) * N + n0 + tx];
    __syncthreads();
#pragma unroll
    for (int i = 0; i < 32; i += 8) {
        const float v = tile[tx * 33 + ty + i];
        const unsigned short h = f2bf(v);
        const size_t o = (size_t)(n0 + ty + i) * K + k0 + tx;
        hi[o] = h;
        lo[o] = f2bf(v - bf2f(h));
    }
}

__global__ __launch_bounds__(256) void prep_kernel(
    const float* __restrict__ traj, const float* __restrict__ W1,
    const float* __restrict__ W2, const float* __restrict__ Wg0,
    const float* __restrict__ Wg1, const float* __restrict__ words,
    unsigned short* __restrict__ A1hi, unsigned short* __restrict__ A1lo,
    unsigned short* __restrict__ WT1h, unsigned short* __restrict__ WT1l,
    unsigned short* __restrict__ WT2h, unsigned short* __restrict__ WT2l,
    unsigned short* __restrict__ WG0h, unsigned short* __restrict__ WG0l,
    unsigned short* __restrict__ WG1h, unsigned short* __restrict__ WG1l,
    float* __restrict__ invw) {
    __shared__ float tile[32 * 33];
    __shared__ float sbuf[4];
    const int blk = blockIdx.x;
    if (blk < 512) {
        const int i = (blk * 256 + threadIdx.x) * 4;
        const float4 v = *(const float4*)(traj + i);
        ushort4 h, l;
        h.x = f2bf(v.x); l.x = f2bf(v.x - bf2f(h.x));
        h.y = f2bf(v.y); l.y = f2bf(v.y - bf2f(h.y));
        h.z = f2bf(v.z); l.z = f2bf(v.z - bf2f(h.z));
        h.w = f2bf(v.w); l.w = f2bf(v.w - bf2f(h.w));
        *(ushort4*)(A1hi + i) = h;
        *(ushort4*)(A1lo + i) = l;
    } else if (blk < 704) {
        const int idx = blk - 512;
        tr_split_tile2(W1, WT1h, WT1l, DTRAJ, D, (idx % 24) * 32, (idx / 24) * 32, tile);
    } else if (blk < 2432) {
        const int idx = blk - 704;
        const int wsel = idx / 576, rem = idx % 576;
        const float* W = (wsel == 0) ? W2 : (wsel == 1) ? Wg0 : Wg1;
        unsigned short* hi = (wsel == 0) ? WT2h : (wsel == 1) ? WG0h : WG1h;
        unsigned short* lo = (wsel == 0) ? WT2l : (wsel == 1) ? WG0l : WG1l;
        tr_split_tile2(W, hi, lo, D, D, (rem % 24) * 32, (rem / 24) * 32, tile);
    } else {
        const int w = blk - 2432;
        const size_t src = (size_t)w * D + threadIdx.x;
        const float x0 = words[src], x1 = words[src + 256], x2 = words[src + 512];
        const float ss = block_reduce_sum256(x0 * x0 + x1 * x1 + x2 * x2, sbuf);
        if (threadIdx.x == 0) invw[w] = 1.0f / fmaxf(sqrtf(ss), 1e-12f);
    }
}

// ---------------- MFMA split-bf16 GEMM (v4: 4 waves, 2 blocks/CU) ----------
// C[2048 x 768] = act(A @ B + bias). A hi/lo row-major (lda=K_); B TRANSPOSED
// hi/lo (768 x K_). Tile 32(M)x96(N), BK=64 double-buffered via
// global_load_lds. 256 thr = 4 waves in 2x2: wave out 16x48 (1x3 frags of
// 16x16x32, split-3: hi*hi + hi*lo + lo*hi). LDS 64 KB -> 2 blocks/CU
// (8 waves/CU = 2/SIMD). Grid (64,8) = 512 blocks = 2/CU.
// XOR slot swizzle (both-sides, rule #21): physical 16B slot p of row holds
// logical chunk p^(row&7); applied on per-lane global SOURCE address at
// stage (LDS dest stays linear) and on the ds_read address. (lane,j)->k map
// is identical for A and B, so MFMA semantics are unchanged.
#define MFMA_BF16(a, b, c) __builtin_amdgcn_mfma_f32_16x16x32_bf16(a, b, c, 0, 0, 0)

template <int EPI, bool TRIM>
__global__ __launch_bounds__(256, 2) void mfma_gemm(
    const unsigned short* __restrict__ Ahi, const unsigned short* __restrict__ Alo,
    const unsigned short* __restrict__ Bthi, const unsigned short* __restrict__ Btlo,
    const float* __restrict__ bias, float* __restrict__ C,
    unsigned short* __restrict__ Ohi, unsigned short* __restrict__ Olo, int K_,
    const int* __restrict__ vlp) {
    const int bm = blockIdx.x * 32;
    if (TRIM && bm >= *vlp) return;  // rows >= valid_len never consumed
    __shared__ short sA[2][2][32 * 64];  // [buf][hi/lo][row*64 + k]
    __shared__ short sB[2][2][96 * 64];
    const int bn = blockIdx.y * 96;
    const int tid = threadIdx.x;
    const int wv = tid >> 6, lane = tid & 63;
    const int lr8 = lane >> 3;                         // staged row within slab
    const int lch = ((lane & 7) ^ (lr8 & 7)) << 3;     // src k-offset (shorts)
    const int g = lane >> 4, r = lane & 15;
    const int wm = (wv >> 1) * 16, wn = (wv & 1) * 48;

    f32x4 acc[3];
#pragma unroll
    for (int j = 0; j < 3; ++j) acc[j] = (f32x4){0.f, 0.f, 0.f, 0.f};

#define STAGE(buf, k0)                                                                     \
    if (wv == 0) {                                                                         \
        _Pragma("unroll") for (int i = 0; i < 4; ++i)                                      \
            stage16(Ahi + (size_t)(bm + i * 8 + lr8) * K_ + (k0) + lch,                    \
                    &sA[buf][0][i * 512]);                                                 \
        _Pragma("unroll") for (int i = 0; i < 4; ++i)                                      \
            stage16(Alo + (size_t)(bm + i * 8 + lr8) * K_ + (k0) + lch,                    \
                    &sA[buf][1][i * 512]);                                                 \
    } else if (wv == 1) {                                                                  \
        _Pragma("unroll") for (int i = 0; i < 8; ++i)                                      \
            stage16(Bthi + (size_t)(bn + i * 8 + lr8) * K_ + (k0) + lch,                   \
                    &sB[buf][0][i * 512]);                                                 \
    } else if (wv == 2) {                                                                  \
        _Pragma("unroll") for (int i = 0; i < 4; ++i)                                      \
            stage16(Bthi + (size_t)(bn + 64 + i * 8 + lr8) * K_ + (k0) + lch,              \
                    &sB[buf][0][(8 + i) * 512]);                                           \
        _Pragma("unroll") for (int i = 0; i < 4; ++i)                                      \
            stage16(Btlo + (size_t)(bn + i * 8 + lr8) * K_ + (k0) + lch,                   \
                    &sB[buf][1][i * 512]);                                                 \
    } else {                                                                               \
        _Pragma("unroll") for (int i = 0; i < 8; ++i)                                      \
            stage16(Btlo + (size_t)(bn + 32 + i * 8 + lr8) * K_ + (k0) + lch,              \
                    &sB[buf][1][(4 + i) * 512]);                                           \
    }

    const int NT = K_ >> 6;
    STAGE(0, 0)
    __syncthreads();
    int cur = 0;
    for (int kt = 0; kt < NT; ++kt) {
        if (kt + 1 < NT) { STAGE(cur ^ 1, (kt + 1) << 6) }  // issue BEFORE compute
#pragma unroll
        for (int ks = 0; ks < 2; ++ks) {
            // logical 16B slot = ks*4+g; physical = logical ^ (r&7)
            const int koff = ((ks * 4 + g) ^ (r & 7)) << 3;
            const bhalf8 ah = *(const bhalf8*)(void*)&sA[cur][0][(wm + r) * 64 + koff];
            const bhalf8 al = *(const bhalf8*)(void*)&sA[cur][1][(wm + r) * 64 + koff];
#pragma unroll
            for (int fn = 0; fn < 3; ++fn) {
                const int brow = (wn + fn * 16 + r) * 64 + koff;
                const bhalf8 bh = *(const bhalf8*)(void*)&sB[cur][0][brow];
                const bhalf8 bl = *(const bhalf8*)(void*)&sB[cur][1][brow];
                acc[fn] = MFMA_BF16(ah, bh, acc[fn]);
                acc[fn] = MFMA_BF16(ah, bl, acc[fn]);
                acc[fn] = MFMA_BF16(al, bh, acc[fn]);
            }
        }
        __syncthreads();  // drains prefetch (vmcnt) + read deps; next tile ready
        cur ^= 1;
    }
#undef STAGE

    // C/D layout (HW-verified m89/m91): col = lane&15, row = 4*(lane>>4)+reg
#pragma unroll
    for (int fn = 0; fn < 3; ++fn) {
        const int col = bn + wn + fn * 16 + r;
        const float bv = bias[col];
#pragma unroll
        for (int j = 0; j < 4; ++j) {
            const int row = bm + wm + g * 4 + j;
            float v = acc[fn][j] + bv;
            if (EPI == 0) {
                C[(size_t)row * D + col] = v;
            } else {
                v = gelu_exact(v);
                const unsigned short h = f2bf(v);
                Ohi[(size_t)row * D + col] = h;
                Olo[(size_t)row * D + col] = f2bf(v - bf2f(h));
            }
        }
    }
}

// ---------------- fused init (LN*scale -> h) + row softmax -> alpha ---------
__global__ __launch_bounds__(256) void init_softmax(
    const float* __restrict__ z, const float* __restrict__ g,
    const float* __restrict__ b, const float* __restrict__ tsp,
    const float* __restrict__ words, const float* __restrict__ invw,
    const int* __restrict__ vlp, float* __restrict__ h, float* __restrict__ alpha) {
    __shared__ float sbuf[4];
    __shared__ float row[D];
    __shared__ float logits[M_WORDS];
    const int blk = blockIdx.x, tid = threadIdx.x;
    if (blk >= T_NODES) {  // word rows: copy into h
        const int w = blk - T_NODES;
        const size_t src = (size_t)w * D + tid;
        const size_t dst = (size_t)(T_NODES + w) * D + tid;
        h[dst] = words[src];
        h[dst + 256] = words[src + 256];
        h[dst + 512] = words[src + 512];
        return;
    }
    float y0, y1, y2;
    ln_row(z + (size_t)blk * D, g, b, sbuf, y0, y1, y2);
    const float sc = fminf(fmaxf(tsp[0], 0.05f), 2.0f);
    y0 *= sc; y1 *= sc; y2 *= sc;
    const size_t o = (size_t)blk * D + tid;
    h[o] = y0; h[o + 256] = y1; h[o + 512] = y2;
    const float ss = block_reduce_sum256(y0 * y0 + y1 * y1 + y2 * y2, sbuf);
    const float iz = 1.0f / fmaxf(sqrtf(ss), 1e-12f);
    if (blk >= *vlp) return;  // alpha rows >= VL never read
    row[tid] = y0; row[tid + 256] = y1; row[tid + 512] = y2;
    __syncthreads();
    const int wid = tid >> 6, lane = tid & 63;
#pragma unroll
    for (int i = 0; i < 8; ++i) {
        const int w = wid * 8 + i;
        const float* wr = words + (size_t)w * D;
        float dot = 0.0f;
        for (int e = lane; e < D; e += 64) dot = fmaf(row[e], wr[e], dot);
        dot = wave_reduce_sum(dot);
        if (lane == 0) logits[w] = dot * iz * invw[w];  // TAU = 1
    }
    __syncthreads();
    if (tid < 64) {
        const float val = (tid < 32) ? logits[tid] : -INFINITY;
        float mx = val;
#pragma unroll
        for (int off = 32; off > 0; off >>= 1) mx = fmaxf(mx, __shfl_xor(mx, off));
        const float e = (tid < 32) ? expf(val - mx) : 0.0f;
        float sum = e;
#pragma unroll
        for (int off = 32; off > 0; off >>= 1) sum += __shfl_xor(sum, off);
        if (tid < 32) alpha[(size_t)blk * M_WORDS + tid] = e / sum;
    }
}

// -------- LN(h)->split bf16 (traj rows); FIN: word rows apply prev-layer fin --
template <int FIN>
__global__ __launch_bounds__(256) void ln_split_fin(
    const float* __restrict__ x, const float* __restrict__ g,
    const float* __restrict__ b, unsigned short* __restrict__ hi,
    unsigned short* __restrict__ lo, const float* __restrict__ wpart,
    const float* __restrict__ bpart, float* __restrict__ h) {
    __shared__ float sbuf[4];
    const int blk = blockIdx.x, tid = threadIdx.x;
    if (blk < T_NODES) {
        float y0, y1, y2;
        ln_row(x + (size_t)blk * D, g, b, sbuf, y0, y1, y2);
        const size_t o = (size_t)blk * D + tid;
        unsigned short hh;
        hh = f2bf(y0); hi[o] = hh;       lo[o] = f2bf(y0 - bf2f(hh));
        hh = f2bf(y1); hi[o + 256] = hh; lo[o + 256] = f2bf(y1 - bf2f(hh));
        hh = f2bf(y2); hi[o + 512] = hh; lo[o + 512] = f2bf(y2 - bf2f(hh));
    } else if (FIN) {
        const int w = blk - T_NODES;
        float bsum = (tid < NCHUNK) ? bpart[tid * M_WORDS + w] : 0.0f;
        const float beta = block_reduce_sum256(bsum, sbuf);
        const float ib = fminf(fmaxf(1.0f / (beta + 1e-6f), 0.2f), 5.0f);
        const float scl = ib / fmaxf(beta, 1.0f);
#pragma unroll
        for (int i = 0; i < 3; ++i) {
            const int c = tid + i * 256;
            float acc = 0.0f;
#pragma unroll 8
            for (int q = 0; q < NCHUNK; ++q)
                acc += wpart[((size_t)q * M_WORDS + w) * D + c];
            h[(size_t)(T_NODES + w) * D + c] += gelu_exact(acc * scl);
        }
    }
}

// -------- per-layer aggregation: temporal update + semantic partials ---------
__global__ __launch_bounds__(256) void gcn_agg_kernel(const float* __restrict__ m,
                                                      const float* __restrict__ alpha,
                                                      const int* __restrict__ vlp,
                                                      float* __restrict__ h,
                                                      float* __restrict__ wpart,
                                                      float* __restrict__ bpart) {
    const int VL = *vlp;
    const int chunk = blockIdx.x, cb = blockIdx.y;
    const int c = cb * 256 + threadIdx.x;
    const int tpc = (VL + NCHUNK - 1) / NCHUNK;
    const int t0 = chunk * tpc;
    const int t1 = min(t0 + tpc, VL);
    float acc[M_WORDS] = {};
    for (int t = t0; t < t1; ++t) {
        const float mv = m[(size_t)t * D + c];
        if (t + 1 < VL) h[(size_t)(t + 1) * D + c] += gelu_exact(mv);
        const float4* a4 = (const float4*)(alpha + (size_t)t * M_WORDS);
#pragma unroll
        for (int q = 0; q < 8; ++q) {
            const float4 a = a4[q];
            acc[q * 4 + 0] = fmaf(a.x, mv, acc[q * 4 + 0]);
            acc[q * 4 + 1] = fmaf(a.y, mv, acc[q * 4 + 1]);
            acc[q * 4 + 2] = fmaf(a.z, mv, acc[q * 4 + 2]);
            acc[q * 4 + 3] = fmaf(a.w, mv, acc[q * 4 + 3]);
        }
    }
#pragma unroll
    for (int w = 0; w < M_WORDS; ++w)
        wpart[((size_t)chunk * M_WORDS + w) * D + c] = acc[w];
    if (cb == 0 && threadIdx.x < M_WORDS) {
        float bs = 0.0f;
        for (int t = t0; t < t1; ++t) bs += alpha[(size_t)t * M_WORDS + threadIdx.x];
        bpart[chunk * M_WORDS + threadIdx.x] = bs;
    }
}

// final-layer word update (h output rows)
__global__ __launch_bounds__(256) void word_fin_kernel(const float* __restrict__ wpart,
                                                       const float* __restrict__ bpart,
                                                       float* __restrict__ h) {
    const int idx = blockIdx.x * 256 + threadIdx.x;
    const int w = idx / D, c = idx - w * D;
    float beta = 0.0f, acc = 0.0f;
#pragma unroll 8
    for (int q = 0; q < NCHUNK; ++q) {
        beta += bpart[q * M_WORDS + w];
        acc += wpart[((size_t)q * M_WORDS + w) * D + c];
    }
    const float ib = fminf(fmaxf(1.0f / (beta + 1e-6f), 0.2f), 5.0f);
    const float v = acc / fmaxf(beta, 1.0f) * ib;
    h[(size_t)(T_NODES + w) * D + c] += gelu_exact(v);
}

extern "C" void kernel_launch(void* const* d_in, const int* in_sizes, int n_in,
                              void* d_out, int out_size, void* d_ws, size_t ws_size,
                              hipStream_t stream) {
    const float* traj = (const float*)d_in[0];
    const float* words = (const float*)d_in[1];
    // d_in[2], d_in[3]: edge indices — deterministic structure, unused.
    const int* vlp = (const int*)d_in[4];
    const float* W1 = (const float*)d_in[5];
    const float* b1 = (const float*)d_in[6];
    const float* W2 = (const float*)d_in[7];
    const float* b2 = (const float*)d_in[8];
    const float* ln_g = (const float*)d_in[9];
    const float* ln_b = (const float*)d_in[10];
    const float* tsc = (const float*)d_in[11];
    const float* g_ln_g[2] = {(const float*)d_in[12], (const float*)d_in[16]};
    const float* g_ln_b[2] = {(const float*)d_in[13], (const float*)d_in[17]};
    const float* g_W[2] = {(const float*)d_in[14], (const float*)d_in[18]};
    const float* g_b[2] = {(const float*)d_in[15], (const float*)d_in[19]};

    char* wsb = (char*)d_ws;
    unsigned short* A1hi = (unsigned short*)(wsb + OFF_A1HI);
    unsigned short* A1lo = (unsigned short*)(wsb + OFF_A1LO);
    unsigned short* Ahi = (unsigned short*)(wsb + OFF_AHI);
    unsigned short* Alo = (unsigned short*)(wsb + OFF_ALO);
    unsigned short* WT1h = (unsigned short*)(wsb + OFF_WT1H);
    unsigned short* WT1l = (unsigned short*)(wsb + OFF_WT1L);
    unsigned short* WT2h = (unsigned short*)(wsb + OFF_WT2H);
    unsigned short* WT2l = (unsigned short*)(wsb + OFF_WT2L);
    unsigned short* WG0h = (unsigned short*)(wsb + OFF_WG0H);
    unsigned short* WG0l = (unsigned short*)(wsb + OFF_WG0L);
    unsigned short* WG1h = (unsigned short*)(wsb + OFF_WG1H);
    unsigned short* WG1l = (unsigned short*)(wsb + OFF_WG1L);
    float* bufB = (float*)(wsb + OFF_BUFB);
    float* alpha = (float*)(wsb + OFF_ALPH);
    float* wpart = (float*)(wsb + OFF_WPRT);
    float* bpart = (float*)(wsb + OFF_BPRT);
    float* invw = (float*)(wsb + OFF_INVW);
    float* h = (float*)d_out;

    const unsigned short* WGh[2] = {WG0h, WG1h};
    const unsigned short* WGl[2] = {WG0l, WG1l};

    const dim3 ggrid(T_NODES / 32, D / 96);  // (64, 8) = 512 blocks = 2/CU

    // 1. all conversions + word norms
    prep_kernel<<<2464, 256, 0, stream>>>(traj, W1, W2, g_W[0], g_W[1], words, A1hi, A1lo,
                                          WT1h, WT1l, WT2h, WT2l, WG0h, WG0l, WG1h, WG1l,
                                          invw);
    // 2-3. MLP
    mfma_gemm<1, false><<<ggrid, 256, 0, stream>>>(A1hi, A1lo, WT1h, WT1l, b1, nullptr,
                                                   Ahi, Alo, DTRAJ, vlp);
    mfma_gemm<0, false><<<ggrid, 256, 0, stream>>>(Ahi, Alo, WT2h, WT2l, b2, bufB,
                                                   nullptr, nullptr, D, vlp);
    // 4. h init + alpha
    init_softmax<<<T_NODES + M_WORDS, 256, 0, stream>>>(bufB, ln_g, ln_b, tsc, words,
                                                        invw, vlp, h, alpha);
    // 5-7. GCN layer 0
    ln_split_fin<0><<<T_NODES, 256, 0, stream>>>(h, g_ln_g[0], g_ln_b[0], Ahi, Alo,
                                                 nullptr, nullptr, h);
    mfma_gemm<0, true><<<ggrid, 256, 0, stream>>>(Ahi, Alo, WGh[0], WGl[0], g_b[0], bufB,
                                                  nullptr, nullptr, D, vlp);
    gcn_agg_kernel<<<dim3(NCHUNK, 3), 256, 0, stream>>>(bufB, alpha, vlp, h, wpart, bpart);
    // 8-10. GCN layer 1 (word-fin of layer 0 fused into ln_split)
    ln_split_fin<1><<<T_NODES + M_WORDS, 256, 0, stream>>>(h, g_ln_g[1], g_ln_b[1], Ahi,
                                                           Alo, wpart, bpart, h);
    mfma_gemm<0, true><<<ggrid, 256, 0, stream>>>(Ahi, Alo, WGh[1], WGl[1], g_b[1], bufB,
                                                  nullptr, nullptr, D, vlp);
    gcn_agg_kernel<<<dim3(NCHUNK, 3), 256, 0, stream>>>(bufB, alpha, vlp, h, wpart, bpart);
    // 11. final word rows
    word_fin_kernel<<<(M_WORDS * D) / 256, 256, 0, stream>>>(wpart, bpart, h);
}